// Round 12
// baseline (1069.845 us; speedup 1.0000x reference)
//
#include <hip/hip_runtime.h>
#include <math.h>

#define BB 4096
#define CC 50257
#define C4 (CC / 4)          // 12564 full float4 chunks; element 50256 = tail "chunk" C4
#define NCHUNK (C4 + 1)      // 12565 breadcrumb entries
#define RAT_AVG_F 0.02f
#define IMAX 0x7fffffff

// Output layout (floats): [0]=bootstrap, [1..4096]=s, [4097..8192]=zmax',
// [8193..12288]=max9d', [12289..16384]=max8d', [16385]=sum(1-s), [16386..20481]=s*max_9
#define OFF_S     1
#define OFF_ZMAX  (1 + BB)
#define OFF_M9D   (1 + 2*BB)
#define OFF_M8D   (1 + 3*BB)
#define OFF_CNT   (1 + 4*BB)
#define OFF_MAX9  (2 + 4*BB)

// Branch-free top-3 (value,index) insert; strict '>' keeps earliest index on
// ties (valid when indices ascend within the caller's stream).
__device__ __forceinline__ void ins3(float x, int j,
                                     float& v0, int& i0,
                                     float& v1, int& i1,
                                     float& v2, int& i2) {
    bool b0 = x > v0, b1 = x > v1, b2 = x > v2;
    float nv2 = fminf(v1, fmaxf(v2, x));   // uses OLD v1
    float nv1 = fminf(v0, fmaxf(v1, x));
    int   ni1 = b0 ? i0 : (b1 ? j : i1);
    int   ni2 = b1 ? i1 : (b2 ? j : i2);
    v0 = fmaxf(v0, x);
    i0 = b0 ? j : i0;
    v1 = nv1; i1 = ni1;
    v2 = nv2; i2 = ni2;
}

// Compound-compare merge (value desc, index asc) — order-independent exact.
__device__ __forceinline__ void merge1(float xv, int jj,
                                       float& v0, int& i0,
                                       float& v1, int& i1,
                                       float& v2, int& i2) {
    bool b0 = (xv > v0) || (xv == v0 && jj < i0);
    bool b1 = (xv > v1) || (xv == v1 && jj < i1);
    bool b2 = (xv > v2) || (xv == v2 && jj < i2);
    float nv1 = b0 ? v0 : (b1 ? xv : v1);
    int   ni1 = b0 ? i0 : (b1 ? jj : i1);
    float nv2 = b1 ? v1 : (b2 ? xv : v2);
    int   ni2 = b1 ? i1 : (b2 ? jj : i2);
    v0 = b0 ? xv : v0; i0 = b0 ? jj : i0;
    v1 = nv1; i1 = ni1;
    v2 = nv2; i2 = ni2;
}

__global__ __launch_bounds__(256) void row_stats_kernel(const float* __restrict__ y_pred,
                                                        const int* __restrict__ y,
                                                        float* __restrict__ out,
                                                        float* __restrict__ boot_ws) {
    // Breadcrumbs: per-chunk max. Top-3 elements of the row are PROVABLY
    // contained in the top-3 chunks ranked by (max desc, chunk-idx asc),
    // including all tie cases (lower chunk = lower element indices).
    __shared__ float smax[NCHUNK];           // 50,260 B
    __shared__ float ssum[4];
    __shared__ float sv0[4], sv1[4], sv2[4];
    __shared__ int   si0[4], si1[4], si2[4];

    const int row = blockIdx.x;
    const int tid = threadIdx.x;
    const float* rp = y_pred + (size_t)row * CC;
    const float4* rp4 = (const float4*)rp;

    // label gather issued early; latency hides under the scan
    float xy = 0.0f;
    if (tid == 0) { int lbl = y[row]; xy = rp[lbl]; }

    // ---------- phase 1: sum of exps + per-chunk max breadcrumbs ----------
    float sumA = 0.0f, sumB = 0.0f;
    int i = tid;
    for (; i + 256 < C4; i += 512) {
        float4 xa = rp4[i];
        float4 xb = rp4[i + 256];
        sumA += (__expf(xa.x) + __expf(xa.y)) + (__expf(xa.z) + __expf(xa.w));
        sumB += (__expf(xb.x) + __expf(xb.y)) + (__expf(xb.z) + __expf(xb.w));
        smax[i]       = fmaxf(fmaxf(xa.x, xa.y), fmaxf(xa.z, xa.w));
        smax[i + 256] = fmaxf(fmaxf(xb.x, xb.y), fmaxf(xb.z, xb.w));
    }
    for (; i < C4; i += 256) {     // at most one leftover chunk per thread
        float4 xa = rp4[i];
        sumA += (__expf(xa.x) + __expf(xa.y)) + (__expf(xa.z) + __expf(xa.w));
        smax[i] = fmaxf(fmaxf(xa.x, xa.y), fmaxf(xa.z, xa.w));
    }
    if (tid == 0) {  // scalar tail element (col 50256) = breadcrumb chunk C4
        float x = rp[CC - 1];
        sumA += __expf(x);
        smax[C4] = x;
    }
    float sum = sumA + sumB;

    // wave (64-lane) sum reduction; lane 0 per wave holds partial
    #pragma unroll
    for (int off = 32; off; off >>= 1) sum += __shfl_down(sum, off);
    if ((tid & 63) == 0) ssum[tid >> 6] = sum;

    __syncthreads();   // publishes smax[] and ssum[]

    // ---------- phase 2: exact top-3 chunks from breadcrumbs ----------
    float v0 = -INFINITY, v1 = -INFINITY, v2 = -INFINITY;
    int   c0 = IMAX, c1 = IMAX, c2 = IMAX;
    for (int k = tid; k < NCHUNK; k += 256)    // stride-256 floats: conflict-free banks
        ins3(smax[k], k, v0, c0, v1, c1, v2, c2);

    #pragma unroll
    for (int off = 32; off; off >>= 1) {
        float ov0 = __shfl_down(v0, off), ov1 = __shfl_down(v1, off), ov2 = __shfl_down(v2, off);
        int   oc0 = __shfl_down(c0, off), oc1 = __shfl_down(c1, off), oc2 = __shfl_down(c2, off);
        merge1(ov0, oc0, v0, c0, v1, c1, v2, c2);
        merge1(ov1, oc1, v0, c0, v1, c1, v2, c2);
        merge1(ov2, oc2, v0, c0, v1, c1, v2, c2);
    }
    if ((tid & 63) == 0) {
        int w = tid >> 6;
        sv0[w] = v0; sv1[w] = v1; sv2[w] = v2;
        si0[w] = c0; si1[w] = c1; si2[w] = c2;
    }
    __syncthreads();

    if (tid == 0) {
        float S = sum;            // wave-0 partial already in 'sum'
        #pragma unroll
        for (int w = 1; w < 4; ++w) {
            S += ssum[w];
            merge1(sv0[w], si0[w], v0, c0, v1, c1, v2, c2);
            merge1(sv1[w], si1[w], v0, c0, v1, c1, v2, c2);
            merge1(sv2[w], si2[w], v0, c0, v1, c1, v2, c2);
        }

        // gather the (distinct) winning chunks' elements; exact global top-3
        float e0v = -INFINITY, e1v = -INFINITY, e2v = -INFINITY;
        int   e0i = IMAX, e1i = IMAX, e2i = IMAX;
        int chs0 = c0, chs1 = c1, chs2 = c2;
        #pragma unroll
        for (int t = 0; t < 3; ++t) {
            int c = (t == 0) ? chs0 : (t == 1) ? chs1 : chs2;
            if (c < C4) {
                float4 q = rp4[c];
                int b = c << 2;
                merge1(q.x, b,     e0v, e0i, e1v, e1i, e2v, e2i);
                merge1(q.y, b + 1, e0v, e0i, e1v, e1i, e2v, e2i);
                merge1(q.z, b + 2, e0v, e0i, e1v, e1i, e2v, e2i);
                merge1(q.w, b + 3, e0v, e0i, e1v, e1i, e2v, e2i);
            } else {
                merge1(rp[CC - 1], CC - 1, e0v, e0i, e1v, e1i, e2v, e2i);
            }
        }

        float logS = __logf(S);
        float fy   = __expf(xy) / S;
        bool  sflg = fy < RAT_AVG_F;

        float x0 = __expf(e0v), x1 = __expf(e1v), x2 = __expf(e2v);
        float boot;
        if (sflg) {
            float inv_w = 1.0f / (x0 + x1 + x2);
            boot = -(x0 * (e0v - logS) + x1 * (e1v - logS) + x2 * (e2v - logS)) * inv_w;
        } else {
            boot = -(xy - logS);
        }
        boot_ws[row]        = boot;
        out[OFF_S + row]    = sflg ? 1.0f : 0.0f;
        out[OFF_ZMAX + row] = sflg ? (float)e0i : -1.0f;
        out[OFF_M9D + row]  = sflg ? (float)e1i : -1.0f;
        out[OFF_M8D + row]  = sflg ? (float)e2i : -1.0f;
        out[OFF_MAX9 + row] = sflg ? (x1 / S) : 0.0f;
    }
}

__global__ __launch_bounds__(256) void final_reduce_kernel(const float* __restrict__ boot_ws,
                                                           float* __restrict__ out) {
    const int tid = threadIdx.x;
    float bsum = 0.0f, csum = 0.0f;
    for (int i = tid; i < BB; i += 256) {
        bsum += boot_ws[i];
        csum += 1.0f - out[OFF_S + i];
    }
    #pragma unroll
    for (int off = 32; off; off >>= 1) {
        bsum += __shfl_down(bsum, off);
        csum += __shfl_down(csum, off);
    }
    __shared__ float sb[4], sc[4];
    if ((tid & 63) == 0) { sb[tid >> 6] = bsum; sc[tid >> 6] = csum; }
    __syncthreads();
    if (tid == 0) {
        float b = 0.0f, c = 0.0f;
        #pragma unroll
        for (int w = 0; w < 4; ++w) { b += sb[w]; c += sc[w]; }
        out[0]       = b / (float)BB;
        out[OFF_CNT] = c;
    }
}

extern "C" void kernel_launch(void* const* d_in, const int* in_sizes, int n_in,
                              void* d_out, int out_size, void* d_ws, size_t ws_size,
                              hipStream_t stream) {
    const float* y_pred = (const float*)d_in[0];
    const int*   y      = (const int*)d_in[1];
    float* out     = (float*)d_out;
    float* boot_ws = (float*)d_ws;  // BB floats

    row_stats_kernel<<<BB, 256, 0, stream>>>(y_pred, y, out, boot_ws);
    final_reduce_kernel<<<1, 256, 0, stream>>>(boot_ws, out);
}